// Round 9
// baseline (3935.334 us; speedup 1.0000x reference)
//
#include <hip/hip_runtime.h>
#include <stddef.h>
#include <stdint.h>

// Problem constants (AnatomicalTextEnhancer): B=16, R=29, D=512, N=20000, k=5
#define B_ 16
#define R_ 29
#define D_ 512
#define DF4 128                            // float4 per row
#define N_ 20000
#define K_ 5
#define TILE 128                           // rows per block (4 waves x 32)
#define NTIX ((N_ + TILE - 1) / TILE)      // 157 tiles per r
#define PCAND (NTIX * K_)                  // 785 candidates per (r,b)
#define NEG_MASK (-1.0e9f)
#define SENT (-3.0e38f)
#define IXMAX 0x7fffffff

// ---------------------------------------------------------------------------
// Kernel 1: L2-normalize queries, write transposed layout qn[r][b][d]
// ---------------------------------------------------------------------------
__global__ __launch_bounds__(64) void knorm_kernel(const float* __restrict__ q,
                                                   float* __restrict__ qn) {
    int pair = blockIdx.x;          // 0 .. B*R-1
    int b = pair / R_;
    int r = pair % R_;
    int lane = threadIdx.x;
    const float4* src = (const float4*)(q + ((size_t)(b * R_ + r)) * D_);
    float4 x0 = src[lane * 2];
    float4 x1 = src[lane * 2 + 1];
    float ss = x0.x * x0.x + x0.y * x0.y + x0.z * x0.z + x0.w * x0.w +
               x1.x * x1.x + x1.y * x1.y + x1.z * x1.z + x1.w * x1.w;
#pragma unroll
    for (int off = 32; off; off >>= 1) ss += __shfl_xor(ss, off);
    float inv = 1.0f / fmaxf(sqrtf(ss), 1e-12f);
    float4 y0, y1;
    y0.x = x0.x * inv; y0.y = x0.y * inv; y0.z = x0.z * inv; y0.w = x0.w * inv;
    y1.x = x1.x * inv; y1.y = x1.y * inv; y1.z = x1.z * inv; y1.w = x1.w * inv;
    float4* dst = (float4*)(qn + ((size_t)(r * B_ + b)) * D_);
    dst[lane * 2] = y0;
    dst[lane * 2 + 1] = y1;
}

// ---------------------------------------------------------------------------
// Kernel 2: M=4 d-split streaming. Block = (r, 128-row tile), 4 waves.
// lane = 8g+s: g = row group (8 rows), s = d-split (8 lanes/row); M=4 rows
// per lane -> 32 rows/wave. Per p-iter: 4 global loads (each instr = 8 rows
// x 128B full lines) + 16 ds_read_b128 q-broadcasts per 4KB of kb (halved
// LDS cost vs M=2). q operands from 32KB LDS panel, one addr reg + imm.
// __launch_bounds__(256,4): cap 128 VGPR (audited need ~100, NO spills).
// Epilogue: per-wave reg top-5 + block merge in LDS overlay.
// ---------------------------------------------------------------------------
__global__ __launch_bounds__(256, 4) void ksim_kernel(const float* __restrict__ kb,
                                                      const float* __restrict__ qn,
                                                      const int* __restrict__ qid,
                                                      const int* __restrict__ kbid,
                                                      float* __restrict__ pvals,
                                                      int* __restrict__ pidx) {
    __shared__ float4 qs[B_ * DF4];       // 32 KB q panel (reused for merge)
    const int r = blockIdx.y;
    const int n0 = blockIdx.x * TILE;
    const int tid = threadIdx.x;

    // stage q panel once (coalesced; qn is L2-resident), single barrier
    {
        const float4* src = (const float4*)(qn + (size_t)r * B_ * D_);
#pragma unroll
        for (int i = 0; i < 8; ++i) qs[tid + 256 * i] = src[tid + 256 * i];
    }
    __syncthreads();

    const int w = tid >> 6;               // wave 0..3 (owns 32 rows)
    const int lane = tid & 63;
    const int g = lane >> 3;              // row group 0..7
    const int s = lane & 7;               // d-split 0..7

    const char* kbb = (const char*)(kb + (size_t)r * N_ * D_);
    int rowi[4];
    unsigned off[4];
#pragma unroll
    for (int m = 0; m < 4; ++m) {
        rowi[m] = n0 + w * 32 + g + m * 8;
        int rc = rowi[m] < N_ ? rowi[m] : N_ - 1;   // clamp tail (masked later)
        off[m] = ((unsigned)rc * D_ + s * 4) * 4u;
    }

    float acc[4][B_];
    float nrm[4];
#pragma unroll
    for (int m = 0; m < 4; ++m) {
        nrm[m] = 0.0f;
#pragma unroll
        for (int b = 0; b < B_; ++b) acc[m][b] = 0.0f;
    }

    // main loop: p = 0..15; lane's chunk = float4 #(8p + s) of each row.
    // One load instr = 8 rows x 128B contiguous (full cache lines).
#pragma unroll
    for (int p = 0; p < 16; ++p) {
        float4 kv[4];
#pragma unroll
        for (int m = 0; m < 4; ++m)
            kv[m] = *(const float4*)(kbb + off[m] + (unsigned)(p * 128));
#pragma unroll
        for (int m = 0; m < 4; ++m)
            nrm[m] += kv[m].x * kv[m].x + kv[m].y * kv[m].y +
                      kv[m].z * kv[m].z + kv[m].w * kv[m].w;
#pragma unroll
        for (int b = 0; b < B_; ++b) {
            const float4 qv = qs[b * DF4 + p * 8 + s];   // 1 addr reg + imm
#pragma unroll
            for (int m = 0; m < 4; ++m)
                acc[m][b] += kv[m].x * qv.x + kv[m].y * qv.y +
                             kv[m].z * qv.z + kv[m].w * qv.w;
        }
    }

    // reduce partials over the 8 s-lanes (all lanes end with totals)
#pragma unroll
    for (int m = 0; m < 4; ++m) {
        nrm[m] += __shfl_xor(nrm[m], 1);
        nrm[m] += __shfl_xor(nrm[m], 2);
        nrm[m] += __shfl_xor(nrm[m], 4);
#pragma unroll
        for (int b = 0; b < B_; ++b) {
            acc[m][b] += __shfl_xor(acc[m][b], 1);
            acc[m][b] += __shfl_xor(acc[m][b], 2);
            acc[m][b] += __shfl_xor(acc[m][b], 4);
        }
    }

    float rinv[4];
    int myid[4];
#pragma unroll
    for (int m = 0; m < 4; ++m) {
        rinv[m] = 1.0f / fmaxf(sqrtf(nrm[m]), 1e-12f);
        myid[m] = (rowi[m] < N_) ? kbid[(size_t)r * N_ + rowi[m]] : -1;
    }

    __syncthreads();   // all waves done reading qs; reuse as merge buffer
    float* vbuf = (float*)qs;                 // [16 b][4 w * 5]
    int* ibuf = (int*)qs + B_ * 4 * K_;       // [16 b][4 w * 5]

    // per-wave top-5 per b over its 32 rows (values 8-fold s-replicated;
    // identical copies keep argmax + removal consistent)
    for (int b = 0; b < B_; ++b) {
        const int qb = qid[b];                // uniform -> scalar load
        float v[4];
#pragma unroll
        for (int m = 0; m < 4; ++m) {
            float sv = acc[m][b] * rinv[m];
            if (myid[m] == qb) sv = NEG_MASK;
            if (rowi[m] >= N_) sv = SENT;
            v[m] = sv;
        }
        for (int k = 0; k < K_; ++k) {
            float bv = v[0];
            int bx = rowi[0];
#pragma unroll
            for (int m = 1; m < 4; ++m)
                if (v[m] > bv || (v[m] == bv && rowi[m] < bx)) { bv = v[m]; bx = rowi[m]; }
#pragma unroll
            for (int off2 = 8; off2 < 64; off2 <<= 1) {
                float ov = __shfl_xor(bv, off2);
                int ox = __shfl_xor(bx, off2);
                if (ov > bv || (ov == bv && ox < bx)) { bv = ov; bx = ox; }
            }
            if (lane == 0) {
                vbuf[b * 20 + w * K_ + k] = bv;
                ibuf[b * 20 + w * K_ + k] = bx;
            }
#pragma unroll
            for (int m = 0; m < 4; ++m)
                if (rowi[m] == bx) v[m] = SENT;   // remove winner (all copies)
        }
    }
    __syncthreads();

    // block merge: wave w, 16-lane group j handles b = 4w + j (20 cands)
    {
        const int j = lane >> 4;
        const int li = lane & 15;
        const int b = w * 4 + j;
        float v0 = vbuf[b * 20 + li];
        int i0 = ibuf[b * 20 + li];
        float v1 = (li < 4) ? vbuf[b * 20 + 16 + li] : SENT;
        int i1 = (li < 4) ? ibuf[b * 20 + 16 + li] : IXMAX;
        for (int k = 0; k < K_; ++k) {
            float bv = v0;
            int bx = i0;
            if (v1 > bv || (v1 == bv && i1 < bx)) { bv = v1; bx = i1; }
#pragma unroll
            for (int off2 = 1; off2 < 16; off2 <<= 1) {
                float ov = __shfl_xor(bv, off2);
                int ox = __shfl_xor(bx, off2);
                if (ov > bv || (ov == bv && ox < bx)) { bv = ov; bx = ox; }
            }
            if (li == 0) {
                size_t o = (((size_t)r * B_ + b) * NTIX + blockIdx.x) * K_ + k;
                pvals[o] = bv;
                pidx[o] = bx;
            }
            if (i0 == bx) v0 = SENT;
            if (i1 == bx) v1 = SENT;
        }
    }
}

// ---------------------------------------------------------------------------
// Kernel 3: reduce 785 candidates per (b,r) to final top-5.
// Per-lane running sorted top-5 + 5 shuffle-argmax extractions.
// d_out layout (all float32): scores[B][R] | vals[B][R][5] | idx[B][R][5]
// ---------------------------------------------------------------------------
__global__ __launch_bounds__(64) void ktop_kernel(const float* __restrict__ pvals,
                                                  const int* __restrict__ pidx,
                                                  float* __restrict__ out) {
    int pair = blockIdx.x;      // 0 .. B*R-1
    int b = pair / R_;
    int r = pair % R_;
    int lane = threadIdx.x;
    const float* pv = pvals + ((size_t)r * B_ + b) * PCAND;
    const int* px = pidx + ((size_t)r * B_ + b) * PCAND;

    float tv[5];
    int tx[5];
#pragma unroll
    for (int t = 0; t < 5; ++t) { tv[t] = SENT; tx[t] = IXMAX; }

    for (int j = 0; j < (PCAND + 63) / 64; ++j) {
        int c = lane + 64 * j;
        if (c < PCAND) {
            float v = pv[c];
            int ix = px[c];
            if (v > tv[4] || (v == tv[4] && ix < tx[4])) {
                tv[4] = v; tx[4] = ix;
#pragma unroll
                for (int t = 4; t > 0; --t)
                    if (tv[t] > tv[t - 1] ||
                        (tv[t] == tv[t - 1] && tx[t] < tx[t - 1])) {
                        float fv = tv[t]; tv[t] = tv[t - 1]; tv[t - 1] = fv;
                        int fx = tx[t]; tx[t] = tx[t - 1]; tx[t - 1] = fx;
                    }
            }
        }
    }

#pragma unroll
    for (int k = 0; k < K_; ++k) {
        float bv = tv[0];
        int bx = tx[0];
#pragma unroll
        for (int off = 32; off; off >>= 1) {
            float ov = __shfl_xor(bv, off);
            int ox = __shfl_xor(bx, off);
            if (ov > bv || (ov == bv && ox < bx)) { bv = ov; bx = ox; }
        }
        if (lane == 0) {
            int p = b * R_ + r;
            if (k == 0) out[p] = bv;                       // similarity_scores
            out[B_ * R_ + (size_t)p * K_ + k] = bv;        // top_vals
            out[B_ * R_ + (size_t)B_ * R_ * K_ + (size_t)p * K_ + k] = (float)bx; // top_idx
        }
        // remove winner from this lane's sorted list (forward shift)
        bool f0 = (tx[0] == bx);
        bool f1 = f0 || (tx[1] == bx);
        bool f2 = f1 || (tx[2] == bx);
        bool f3 = f2 || (tx[3] == bx);
        bool f4 = f3 || (tx[4] == bx);
        if (f0) { tv[0] = tv[1]; tx[0] = tx[1]; }
        if (f1) { tv[1] = tv[2]; tx[1] = tx[2]; }
        if (f2) { tv[2] = tv[3]; tx[2] = tx[3]; }
        if (f3) { tv[3] = tv[4]; tx[3] = tx[4]; }
        if (f4) { tv[4] = SENT; tx[4] = IXMAX; }
    }
}

// ---------------------------------------------------------------------------
extern "C" void kernel_launch(void* const* d_in, const int* in_sizes, int n_in,
                              void* d_out, int out_size, void* d_ws, size_t ws_size,
                              hipStream_t stream) {
    const float* q    = (const float*)d_in[0];   // [B,R,D] fp32
    const float* kb   = (const float*)d_in[1];   // [R,N,D] fp32
    const int*   qid  = (const int*)d_in[2];     // [B]
    const int*   kbid = (const int*)d_in[3];     // [R,N]
    float* out = (float*)d_out;

    float* qn    = (float*)d_ws;                             // R*B*D floats
    float* pvals = qn + (size_t)R_ * B_ * D_;                // R*B*PCAND floats
    int*   pidx  = (int*)(pvals + (size_t)R_ * B_ * PCAND);

    knorm_kernel<<<B_ * R_, 64, 0, stream>>>(q, qn);
    dim3 g2(NTIX, R_);
    ksim_kernel<<<g2, 256, 0, stream>>>(kb, qn, qid, kbid, pvals, pidx);
    ktop_kernel<<<B_ * R_, 64, 0, stream>>>(pvals, pidx, out);
}

// Round 10
// 805.220 us; speedup vs baseline: 4.8873x; 4.8873x over previous
//
#include <hip/hip_runtime.h>
#include <stddef.h>
#include <stdint.h>

// Problem constants (AnatomicalTextEnhancer): B=16, R=29, D=512, N=20000, k=5
#define B_ 16
#define R_ 29
#define D_ 512
#define N_ 20000
#define K_ 5
#define TROWS 32                           // rows per tile; 20000 = 625*32 exact
#define NTIX (N_ / TROWS)                  // 625 tiles per r (no tail!)
#define NTILES (R_ * NTIX)                 // 18125
#define GRID2 256                          // 1 block/CU
#define SLOTS GRID2                        // emit slots per (r,b)
#define PCAND (SLOTS * K_)                 // 1280 candidates per (r,b) in ktop
#define NEG_MASK (-1.0e9f)
#define SENT (-3.0e38f)
#define IXMAX 0x7fffffff

// ---------------------------------------------------------------------------
// Kernel 1: L2-normalize queries, write transposed layout qn[r][b][d]
// ---------------------------------------------------------------------------
__global__ __launch_bounds__(64) void knorm_kernel(const float* __restrict__ q,
                                                   float* __restrict__ qn) {
    int pair = blockIdx.x;          // 0 .. B*R-1
    int b = pair / R_;
    int r = pair % R_;
    int lane = threadIdx.x;
    const float4* src = (const float4*)(q + ((size_t)(b * R_ + r)) * D_);
    float4 x0 = src[lane * 2];
    float4 x1 = src[lane * 2 + 1];
    float ss = x0.x * x0.x + x0.y * x0.y + x0.z * x0.z + x0.w * x0.w +
               x1.x * x1.x + x1.y * x1.y + x1.z * x1.z + x1.w * x1.w;
#pragma unroll
    for (int off = 32; off; off >>= 1) ss += __shfl_xor(ss, off);
    float inv = 1.0f / fmaxf(sqrtf(ss), 1e-12f);
    float4 y0, y1;
    y0.x = x0.x * inv; y0.y = x0.y * inv; y0.z = x0.z * inv; y0.w = x0.w * inv;
    y1.x = x1.x * inv; y1.y = x1.y * inv; y1.z = x1.z * inv; y1.w = x1.w * inv;
    float4* dst = (float4*)(qn + ((size_t)(r * B_ + b)) * D_);
    dst[lane * 2] = y0;
    dst[lane * 2 + 1] = y1;
}

// ---------------------------------------------------------------------------
// Kernel 1b: fill pvals with SENT (emit slots are sparse per (r,b))
// ---------------------------------------------------------------------------
__global__ __launch_bounds__(256) void kinit_kernel(float* __restrict__ pvals,
                                                    int total) {
    int i = blockIdx.x * 256 + threadIdx.x;
    if (i < total) pvals[i] = SENT;
}

// ---------------------------------------------------------------------------
// Kernel 2: sequential-burst staged sims.
// Grid = 256 blocks (1/CU), 256 threads; block loops over a contiguous range
// of (r, tile) pairs. Per tile (32 rows x 2KB = 64KB):
//   STAGE: per wave, 16 global_load_lds, each 1KB CONTIGUOUS WITHIN ONE ROW,
//   consecutive instrs sweep rows linearly -> pure sequential DRAM stream
//   (>=1KB per page visit; fixes the 2.5 TB/s activation wall).
//   Double-buffer 2x64KB, counted vmcnt(16), raw s_barrier x2 per tile.
// COMPUTE: wave w owns b-quad {4w..4w+3}; lane=(g=lane>>3, s=lane&7);
//   rows g+8m (m=0..3); q is in 256 VGPRs (lane's s-slice, loaded per r) ->
//   zero LDS/SMEM q traffic. LDS kb reads: per-octet s spans all 8 bank
//   groups -> conflict-free, linear layout.
// 1 block/CU (128KB LDS) = 1 wave/SIMD -> up to 512 VGPR, no spill.
// Running top-5 per (wave,b) in registers; emit per r into slot bid.
// ---------------------------------------------------------------------------
__global__ __launch_bounds__(256) void ksim_kernel(const float* __restrict__ kb,
                                                   const float* __restrict__ qn,
                                                   const int* __restrict__ qid,
                                                   const int* __restrict__ kbid,
                                                   float* __restrict__ pvals,
                                                   int* __restrict__ pidx) {
    __shared__ float4 kbt[2][TROWS * 128];   // 2 x 64 KB
    const int tid = threadIdx.x;
    const int w = tid >> 6;               // wave 0..3
    const int lane = tid & 63;
    const int g = lane >> 3;              // row group 0..7
    const int s = lane & 7;               // d-split 0..7
    const int bid = blockIdx.x;

    const int t0 = (int)(((long long)bid * NTILES) / GRID2);
    const int t1 = (int)(((long long)(bid + 1) * NTILES) / GRID2);

    float4 qreg[4][16];                   // q[b-quad][p] for this lane's s
    float tv[4][K_];
    int tx[4][K_];
    int qb[4];
    int cur_r = -1;
    int buf = 0;

#define STAGE(tix_, bp_) do {                                                  \
    const float* rb_ = kb + ((size_t)cur_r * N_ +                              \
                             (size_t)(tix_) * TROWS + (size_t)(w * 8)) * D_;   \
    char* db_ = (char*)(&kbt[(bp_)][0]) + w * 16384;                           \
    _Pragma("unroll")                                                          \
    for (int j_ = 0; j_ < 16; ++j_) {                                          \
        const float* sp_ = rb_ + (j_ >> 1) * D_ + (j_ & 1) * 256 + lane * 4;   \
        __builtin_amdgcn_global_load_lds(                                      \
            (const __attribute__((address_space(1))) void*)sp_,                \
            (__attribute__((address_space(3))) void*)                          \
                (db_ + (j_ >> 1) * 2048 + (j_ & 1) * 1024), 16, 0, 0);         \
    }                                                                          \
} while (0)

#define EMIT(rr_) do {                                                         \
    _Pragma("unroll")                                                          \
    for (int bi_ = 0; bi_ < 4; ++bi_) {                                        \
        for (int k_ = 0; k_ < K_; ++k_) {                                      \
            float bv_ = tv[bi_][0];                                            \
            int bx_ = tx[bi_][0];                                              \
            _Pragma("unroll")                                                  \
            for (int of_ = 1; of_ < 64; of_ <<= 1) {                           \
                float ov_ = __shfl_xor(bv_, of_);                              \
                int ox_ = __shfl_xor(bx_, of_);                                \
                if (ov_ > bv_ || (ov_ == bv_ && ox_ < bx_)) { bv_ = ov_; bx_ = ox_; } \
            }                                                                  \
            if (lane == 0) {                                                   \
                size_t o_ = (((size_t)(rr_) * B_ + (w * 4 + bi_)) * SLOTS + bid) * K_ + k_; \
                pvals[o_] = bv_;                                               \
                pidx[o_] = bx_;                                                \
            }                                                                  \
            bool f0_ = (tx[bi_][0] == bx_);                                    \
            bool f1_ = f0_ || (tx[bi_][1] == bx_);                             \
            bool f2_ = f1_ || (tx[bi_][2] == bx_);                             \
            bool f3_ = f2_ || (tx[bi_][3] == bx_);                             \
            bool f4_ = f3_ || (tx[bi_][4] == bx_);                             \
            if (f0_) { tv[bi_][0] = tv[bi_][1]; tx[bi_][0] = tx[bi_][1]; }     \
            if (f1_) { tv[bi_][1] = tv[bi_][2]; tx[bi_][1] = tx[bi_][2]; }     \
            if (f2_) { tv[bi_][2] = tv[bi_][3]; tx[bi_][2] = tx[bi_][3]; }     \
            if (f3_) { tv[bi_][3] = tv[bi_][4]; tx[bi_][3] = tx[bi_][4]; }     \
            if (f4_) { tv[bi_][4] = SENT; tx[bi_][4] = IXMAX; }                \
        }                                                                      \
    }                                                                          \
} while (0)

    for (int ti = t0; ti < t1; ++ti) {
        const int r = ti / NTIX;
        const int tix = ti % NTIX;
        const int n0 = tix * TROWS;

        if (r != cur_r) {
            if (cur_r >= 0) EMIT(cur_r);
#pragma unroll
            for (int bi = 0; bi < 4; ++bi) {
#pragma unroll
                for (int t = 0; t < K_; ++t) { tv[bi][t] = SENT; tx[bi][t] = IXMAX; }
            }
            const float* qrb = qn + (size_t)r * B_ * D_;
#pragma unroll
            for (int bi = 0; bi < 4; ++bi) {
                qb[bi] = qid[w * 4 + bi];
#pragma unroll
                for (int p = 0; p < 16; ++p)
                    qreg[bi][p] = *(const float4*)(qrb + (w * 4 + bi) * D_ + p * 32 + s * 4);
            }
            cur_r = r;
            STAGE(tix, buf);              // prologue stage for this r
        }

        const bool next_same = (ti + 1 < t1) && ((ti + 1) < (r + 1) * NTIX);
        if (next_same) {
            STAGE(tix + 1, buf ^ 1);
            asm volatile("s_waitcnt vmcnt(16)" ::: "memory");
        } else {
            asm volatile("s_waitcnt vmcnt(0)" ::: "memory");
        }
        __builtin_amdgcn_s_barrier();
        __builtin_amdgcn_sched_barrier(0);

        // ---- compute tile from kbt[buf] ----
        float acc[4][4];                  // [m][bi]
        float nrm[4];
#pragma unroll
        for (int m = 0; m < 4; ++m) {
            nrm[m] = 0.0f;
#pragma unroll
            for (int bi = 0; bi < 4; ++bi) acc[m][bi] = 0.0f;
        }
        const float4* kt = &kbt[buf][0];
#pragma unroll
        for (int p = 0; p < 16; ++p) {
            float4 kv[4];
#pragma unroll
            for (int m = 0; m < 4; ++m) kv[m] = kt[(g + 8 * m) * 128 + p * 8 + s];
#pragma unroll
            for (int m = 0; m < 4; ++m)
                nrm[m] += kv[m].x * kv[m].x + kv[m].y * kv[m].y +
                          kv[m].z * kv[m].z + kv[m].w * kv[m].w;
#pragma unroll
            for (int bi = 0; bi < 4; ++bi) {
#pragma unroll
                for (int m = 0; m < 4; ++m)
                    acc[m][bi] += kv[m].x * qreg[bi][p].x + kv[m].y * qreg[bi][p].y +
                                  kv[m].z * qreg[bi][p].z + kv[m].w * qreg[bi][p].w;
            }
        }

        // reduce over the 8 s-lanes (all lanes end with totals, 8x dup)
#pragma unroll
        for (int m = 0; m < 4; ++m) {
            nrm[m] += __shfl_xor(nrm[m], 1);
            nrm[m] += __shfl_xor(nrm[m], 2);
            nrm[m] += __shfl_xor(nrm[m], 4);
#pragma unroll
            for (int bi = 0; bi < 4; ++bi) {
                acc[m][bi] += __shfl_xor(acc[m][bi], 1);
                acc[m][bi] += __shfl_xor(acc[m][bi], 2);
                acc[m][bi] += __shfl_xor(acc[m][bi], 4);
            }
        }

        // finalize + insert into running top-5 (all rows real: 625*32 = N)
#pragma unroll
        for (int m = 0; m < 4; ++m) {
            const int row = n0 + g + 8 * m;
            const float rinv = 1.0f / fmaxf(sqrtf(nrm[m]), 1e-12f);
            const int myid = kbid[(size_t)r * N_ + row];
#pragma unroll
            for (int bi = 0; bi < 4; ++bi) {
                float v = acc[m][bi] * rinv;
                if (myid == qb[bi]) v = NEG_MASK;
                if (v > tv[bi][4] || (v == tv[bi][4] && row < tx[bi][4])) {
                    tv[bi][4] = v; tx[bi][4] = row;
                    if (tv[bi][4] > tv[bi][3] || (tv[bi][4] == tv[bi][3] && tx[bi][4] < tx[bi][3])) {
                        float fv = tv[bi][4]; tv[bi][4] = tv[bi][3]; tv[bi][3] = fv;
                        int fx = tx[bi][4]; tx[bi][4] = tx[bi][3]; tx[bi][3] = fx;
                    }
                    if (tv[bi][3] > tv[bi][2] || (tv[bi][3] == tv[bi][2] && tx[bi][3] < tx[bi][2])) {
                        float fv = tv[bi][3]; tv[bi][3] = tv[bi][2]; tv[bi][2] = fv;
                        int fx = tx[bi][3]; tx[bi][3] = tx[bi][2]; tx[bi][2] = fx;
                    }
                    if (tv[bi][2] > tv[bi][1] || (tv[bi][2] == tv[bi][1] && tx[bi][2] < tx[bi][1])) {
                        float fv = tv[bi][2]; tv[bi][2] = tv[bi][1]; tv[bi][1] = fv;
                        int fx = tx[bi][2]; tx[bi][2] = tx[bi][1]; tx[bi][1] = fx;
                    }
                    if (tv[bi][1] > tv[bi][0] || (tv[bi][1] == tv[bi][0] && tx[bi][1] < tx[bi][0])) {
                        float fv = tv[bi][1]; tv[bi][1] = tv[bi][0]; tv[bi][0] = fv;
                        int fx = tx[bi][1]; tx[bi][1] = tx[bi][0]; tx[bi][0] = fx;
                    }
                }
            }
        }

        __builtin_amdgcn_sched_barrier(0);
        __builtin_amdgcn_s_barrier();     // all done reading kbt[buf]
        buf ^= 1;
    }
    if (cur_r >= 0) EMIT(cur_r);

#undef STAGE
#undef EMIT
}

// ---------------------------------------------------------------------------
// Kernel 3: reduce 1280 slot-candidates per (b,r) to final top-5.
// d_out layout (all float32): scores[B][R] | vals[B][R][5] | idx[B][R][5]
// ---------------------------------------------------------------------------
__global__ __launch_bounds__(64) void ktop_kernel(const float* __restrict__ pvals,
                                                  const int* __restrict__ pidx,
                                                  float* __restrict__ out) {
    int pair = blockIdx.x;      // 0 .. B*R-1
    int b = pair / R_;
    int r = pair % R_;
    int lane = threadIdx.x;
    const float* pv = pvals + ((size_t)r * B_ + b) * PCAND;
    const int* px = pidx + ((size_t)r * B_ + b) * PCAND;

    float tv[5];
    int tx[5];
#pragma unroll
    for (int t = 0; t < 5; ++t) { tv[t] = SENT; tx[t] = IXMAX; }

    for (int j = 0; j < PCAND / 64; ++j) {
        int c = lane + 64 * j;
        float v = pv[c];
        int ix = px[c];
        if (v > tv[4] || (v == tv[4] && ix < tx[4])) {
            tv[4] = v; tx[4] = ix;
#pragma unroll
            for (int t = 4; t > 0; --t)
                if (tv[t] > tv[t - 1] ||
                    (tv[t] == tv[t - 1] && tx[t] < tx[t - 1])) {
                    float fv = tv[t]; tv[t] = tv[t - 1]; tv[t - 1] = fv;
                    int fx = tx[t]; tx[t] = tx[t - 1]; tx[t - 1] = fx;
                }
        }
    }

#pragma unroll
    for (int k = 0; k < K_; ++k) {
        float bv = tv[0];
        int bx = tx[0];
#pragma unroll
        for (int off = 32; off; off >>= 1) {
            float ov = __shfl_xor(bv, off);
            int ox = __shfl_xor(bx, off);
            if (ov > bv || (ov == bv && ox < bx)) { bv = ov; bx = ox; }
        }
        if (lane == 0) {
            int p = b * R_ + r;
            if (k == 0) out[p] = bv;                       // similarity_scores
            out[B_ * R_ + (size_t)p * K_ + k] = bv;        // top_vals
            out[B_ * R_ + (size_t)B_ * R_ * K_ + (size_t)p * K_ + k] = (float)bx; // top_idx
        }
        bool f0 = (tx[0] == bx);
        bool f1 = f0 || (tx[1] == bx);
        bool f2 = f1 || (tx[2] == bx);
        bool f3 = f2 || (tx[3] == bx);
        bool f4 = f3 || (tx[4] == bx);
        if (f0) { tv[0] = tv[1]; tx[0] = tx[1]; }
        if (f1) { tv[1] = tv[2]; tx[1] = tx[2]; }
        if (f2) { tv[2] = tv[3]; tx[2] = tx[3]; }
        if (f3) { tv[3] = tv[4]; tx[3] = tx[4]; }
        if (f4) { tv[4] = SENT; tx[4] = IXMAX; }
    }
}

// ---------------------------------------------------------------------------
extern "C" void kernel_launch(void* const* d_in, const int* in_sizes, int n_in,
                              void* d_out, int out_size, void* d_ws, size_t ws_size,
                              hipStream_t stream) {
    const float* q    = (const float*)d_in[0];   // [B,R,D] fp32
    const float* kb   = (const float*)d_in[1];   // [R,N,D] fp32
    const int*   qid  = (const int*)d_in[2];     // [B]
    const int*   kbid = (const int*)d_in[3];     // [R,N]
    float* out = (float*)d_out;

    float* qn    = (float*)d_ws;                             // R*B*D floats
    float* pvals = qn + (size_t)R_ * B_ * D_;                // R*B*SLOTS*K floats
    int*   pidx  = (int*)(pvals + (size_t)R_ * B_ * SLOTS * K_);

    const int ptotal = R_ * B_ * SLOTS * K_;                 // 593920

    knorm_kernel<<<B_ * R_, 64, 0, stream>>>(q, qn);
    kinit_kernel<<<(ptotal + 255) / 256, 256, 0, stream>>>(pvals, ptotal);
    ksim_kernel<<<GRID2, 256, 0, stream>>>(kb, qn, qid, kbid, pvals, pidx);
    ktop_kernel<<<B_ * R_, 64, 0, stream>>>(pvals, pidx, out);
}

// Round 11
// 597.086 us; speedup vs baseline: 6.5909x; 1.3486x over previous
//
#include <hip/hip_runtime.h>
#include <stddef.h>
#include <stdint.h>

// Problem constants (AnatomicalTextEnhancer): B=16, R=29, D=512, N=20000, k=5
#define B_ 16
#define R_ 29
#define D_ 512
#define DF4 128                            // float4 per row
#define N_ 20000
#define K_ 5
#define TILE 256                           // rows per block (16 waves x 16)
#define NTIX ((N_ + TILE - 1) / TILE)      // 79 tiles per r
#define PCAND (NTIX * K_)                  // 395 candidates per (r,b)
#define NEG_MASK (-1.0e9f)
#define SENT (-3.0e38f)
#define IXMAX 0x7fffffff

// ---------------------------------------------------------------------------
// Kernel 1: L2-normalize queries, write transposed layout qn[r][b][d]
// ---------------------------------------------------------------------------
__global__ __launch_bounds__(64) void knorm_kernel(const float* __restrict__ q,
                                                   float* __restrict__ qn) {
    int pair = blockIdx.x;          // 0 .. B*R-1
    int b = pair / R_;
    int r = pair % R_;
    int lane = threadIdx.x;
    const float4* src = (const float4*)(q + ((size_t)(b * R_ + r)) * D_);
    float4 x0 = src[lane * 2];
    float4 x1 = src[lane * 2 + 1];
    float ss = x0.x * x0.x + x0.y * x0.y + x0.z * x0.z + x0.w * x0.w +
               x1.x * x1.x + x1.y * x1.y + x1.z * x1.z + x1.w * x1.w;
#pragma unroll
    for (int off = 32; off; off >>= 1) ss += __shfl_xor(ss, off);
    float inv = 1.0f / fmaxf(sqrtf(ss), 1e-12f);
    float4 y0, y1;
    y0.x = x0.x * inv; y0.y = x0.y * inv; y0.z = x0.z * inv; y0.w = x0.w * inv;
    y1.x = x1.x * inv; y1.y = x1.y * inv; y1.z = x1.z * inv; y1.w = x1.w * inv;
    float4* dst = (float4*)(qn + ((size_t)(r * B_ + b)) * D_);
    dst[lane * 2] = y0;
    dst[lane * 2 + 1] = y1;
}

// ---------------------------------------------------------------------------
// Kernel 2: round-8 structure WITHOUT the VGPR guillotine.
// 1024 threads (16 waves), TILE=256 rows, M=2 rows/lane, 8-lane d-split
// (each load instr = 8 rows x 128B full cache lines). NO second
// __launch_bounds__ arg: target ~55-64 live VGPR -> 8 waves/SIMD,
// 2 blocks/CU (32KB LDS each) = 32 waves/CU. BW here scales with waves
// (R4: 16w -> 2.5 TB/s; R8: 32w -> 3.7 TB/s even while spilling).
// q panel in LDS, broadcast b128 reads (8 unique addrs covering all 32
// banks: R8-measured ZERO conflicts). kb via SGPR base + 32-bit voffset.
// Epilogue: per-wave reg top-5 -> block merge in LDS overlay -> 5 cands
// per (block,b) to ktop.
// ---------------------------------------------------------------------------
__global__ __launch_bounds__(1024) void ksim_kernel(const float* __restrict__ kb,
                                                    const float* __restrict__ qn,
                                                    const int* __restrict__ qid,
                                                    const int* __restrict__ kbid,
                                                    float* __restrict__ pvals,
                                                    int* __restrict__ pidx) {
    __shared__ float4 qs[B_ * DF4];       // 32 KB q panel (reused for merge)
    const int r = blockIdx.y;
    const int n0 = blockIdx.x * TILE;
    const int tid = threadIdx.x;

    // stage q panel once (coalesced; qn is L2-resident), single barrier
    {
        const float4* src = (const float4*)(qn + (size_t)r * B_ * D_);
#pragma unroll
        for (int i = 0; i < 8; ++i) qs[tid + 1024 * i] = src[tid + 1024 * i];
    }
    __syncthreads();

    const int w = tid >> 6;               // wave 0..15 (owns 16 rows)
    const int lane = tid & 63;
    const int g = lane >> 3;              // row group 0..7
    const int s = lane & 7;               // d-split 0..7

    const char* kbb = (const char*)(kb + (size_t)r * N_ * D_);  // uniform->SGPR
    int rowi[2];
    unsigned off[2];
#pragma unroll
    for (int m = 0; m < 2; ++m) {
        rowi[m] = n0 + w * 16 + g + m * 8;
        int rc = rowi[m] < N_ ? rowi[m] : N_ - 1;   // clamp tail (masked later)
        off[m] = ((unsigned)rc * D_ + s * 4) * 4u;
    }

    float acc[2][B_];
    float nrm[2];
#pragma unroll
    for (int m = 0; m < 2; ++m) {
        nrm[m] = 0.0f;
#pragma unroll
        for (int b = 0; b < B_; ++b) acc[m][b] = 0.0f;
    }

    // main loop: p = 0..15; lane's chunk = float4 #(8p + s) of each row.
    // unroll 2: bounds register pressure; TLP (32 waves/CU) hides latency.
#pragma unroll 2
    for (int p = 0; p < 16; ++p) {
        float4 kv0 = *(const float4*)(kbb + off[0] + (unsigned)(p * 128));
        float4 kv1 = *(const float4*)(kbb + off[1] + (unsigned)(p * 128));
        nrm[0] += kv0.x * kv0.x + kv0.y * kv0.y + kv0.z * kv0.z + kv0.w * kv0.w;
        nrm[1] += kv1.x * kv1.x + kv1.y * kv1.y + kv1.z * kv1.z + kv1.w * kv1.w;
#pragma unroll
        for (int b = 0; b < B_; ++b) {
            const float4 qv = qs[b * DF4 + p * 8 + s];   // bcast, 1 addr + imm
            acc[0][b] += kv0.x * qv.x + kv0.y * qv.y + kv0.z * qv.z + kv0.w * qv.w;
            acc[1][b] += kv1.x * qv.x + kv1.y * qv.y + kv1.z * qv.z + kv1.w * qv.w;
        }
    }

    // reduce partials over the 8 s-lanes (all lanes end with totals)
#pragma unroll
    for (int m = 0; m < 2; ++m) {
        nrm[m] += __shfl_xor(nrm[m], 1);
        nrm[m] += __shfl_xor(nrm[m], 2);
        nrm[m] += __shfl_xor(nrm[m], 4);
#pragma unroll
        for (int b = 0; b < B_; ++b) {
            acc[m][b] += __shfl_xor(acc[m][b], 1);
            acc[m][b] += __shfl_xor(acc[m][b], 2);
            acc[m][b] += __shfl_xor(acc[m][b], 4);
        }
    }

    float rinv[2];
    int myid[2];
#pragma unroll
    for (int m = 0; m < 2; ++m) {
        rinv[m] = 1.0f / fmaxf(sqrtf(nrm[m]), 1e-12f);
        myid[m] = (rowi[m] < N_) ? kbid[(size_t)r * N_ + rowi[m]] : -1;
    }

    __syncthreads();   // all waves done reading qs; reuse it as merge buffer
    float* vbuf = (float*)qs;                 // [16 b][16 w][5]
    int* ibuf = (int*)qs + B_ * 16 * K_;      // [16 b][16 w][5]

    // per-wave top-5 per b over its 16 rows (values 8-fold s-replicated;
    // identical copies keep argmax + removal consistent), written to LDS
    for (int b = 0; b < B_; ++b) {
        const int qb = qid[b];                // uniform -> scalar load
        float v[2];
#pragma unroll
        for (int m = 0; m < 2; ++m) {
            float sv = acc[m][b] * rinv[m];
            if (myid[m] == qb) sv = NEG_MASK;
            if (rowi[m] >= N_) sv = SENT;
            v[m] = sv;
        }
        for (int k = 0; k < K_; ++k) {
            float bv = v[0];
            int bx = rowi[0];
            if (v[1] > bv || (v[1] == bv && rowi[1] < bx)) { bv = v[1]; bx = rowi[1]; }
#pragma unroll
            for (int off2 = 8; off2 < 64; off2 <<= 1) {
                float ov = __shfl_xor(bv, off2);
                int ox = __shfl_xor(bx, off2);
                if (ov > bv || (ov == bv && ox < bx)) { bv = ov; bx = ox; }
            }
            if (lane == 0) {
                vbuf[(b * 16 + w) * K_ + k] = bv;
                ibuf[(b * 16 + w) * K_ + k] = bx;
            }
#pragma unroll
            for (int m = 0; m < 2; ++m)
                if (rowi[m] == bx) v[m] = SENT;   // remove winner (all copies)
        }
    }
    __syncthreads();

    // block-level merge: wave w handles b = w; 80 candidates -> top-5
    {
        const int b = w;
        float v0 = SENT, v1 = SENT;
        int i0 = IXMAX, i1 = IXMAX;
        if (lane < 80) { v0 = vbuf[b * 80 + lane]; i0 = ibuf[b * 80 + lane]; }
        if (lane < 16) { v1 = vbuf[b * 80 + 64 + lane]; i1 = ibuf[b * 80 + 64 + lane]; }
        for (int k = 0; k < K_; ++k) {
            float bv = v0;
            int bx = i0;
            if (v1 > bv || (v1 == bv && i1 < bx)) { bv = v1; bx = i1; }
#pragma unroll
            for (int off2 = 1; off2 < 64; off2 <<= 1) {
                float ov = __shfl_xor(bv, off2);
                int ox = __shfl_xor(bx, off2);
                if (ov > bv || (ov == bv && ox < bx)) { bv = ov; bx = ox; }
            }
            if (lane == 0) {
                size_t o = (((size_t)r * B_ + b) * NTIX + blockIdx.x) * K_ + k;
                pvals[o] = bv;
                pidx[o] = bx;
            }
            if (i0 == bx) v0 = SENT;
            if (i1 == bx) v1 = SENT;
        }
    }
}

// ---------------------------------------------------------------------------
// Kernel 3: reduce 395 candidates per (b,r) to final top-5.
// Per-lane running sorted top-5 + 5 shuffle-argmax extractions.
// d_out layout (all float32): scores[B][R] | vals[B][R][5] | idx[B][R][5]
// ---------------------------------------------------------------------------
__global__ __launch_bounds__(64) void ktop_kernel(const float* __restrict__ pvals,
                                                  const int* __restrict__ pidx,
                                                  float* __restrict__ out) {
    int pair = blockIdx.x;      // 0 .. B*R-1
    int b = pair / R_;
    int r = pair % R_;
    int lane = threadIdx.x;
    const float* pv = pvals + ((size_t)r * B_ + b) * PCAND;
    const int* px = pidx + ((size_t)r * B_ + b) * PCAND;

    float tv[5];
    int tx[5];
#pragma unroll
    for (int t = 0; t < 5; ++t) { tv[t] = SENT; tx[t] = IXMAX; }

    for (int j = 0; j < (PCAND + 63) / 64; ++j) {
        int c = lane + 64 * j;
        if (c < PCAND) {
            float v = pv[c];
            int ix = px[c];
            if (v > tv[4] || (v == tv[4] && ix < tx[4])) {
                tv[4] = v; tx[4] = ix;
#pragma unroll
                for (int t = 4; t > 0; --t)
                    if (tv[t] > tv[t - 1] ||
                        (tv[t] == tv[t - 1] && tx[t] < tx[t - 1])) {
                        float fv = tv[t]; tv[t] = tv[t - 1]; tv[t - 1] = fv;
                        int fx = tx[t]; tx[t] = tx[t - 1]; tx[t - 1] = fx;
                    }
            }
        }
    }

#pragma unroll
    for (int k = 0; k < K_; ++k) {
        float bv = tv[0];
        int bx = tx[0];
#pragma unroll
        for (int off = 32; off; off >>= 1) {
            float ov = __shfl_xor(bv, off);
            int ox = __shfl_xor(bx, off);
            if (ov > bv || (ov == bv && ox < bx)) { bv = ov; bx = ox; }
        }
        if (lane == 0) {
            int p = b * R_ + r;
            if (k == 0) out[p] = bv;                       // similarity_scores
            out[B_ * R_ + (size_t)p * K_ + k] = bv;        // top_vals
            out[B_ * R_ + (size_t)B_ * R_ * K_ + (size_t)p * K_ + k] = (float)bx; // top_idx
        }
        // remove winner from this lane's sorted list (forward shift)
        bool f0 = (tx[0] == bx);
        bool f1 = f0 || (tx[1] == bx);
        bool f2 = f1 || (tx[2] == bx);
        bool f3 = f2 || (tx[3] == bx);
        bool f4 = f3 || (tx[4] == bx);
        if (f0) { tv[0] = tv[1]; tx[0] = tx[1]; }
        if (f1) { tv[1] = tv[2]; tx[1] = tx[2]; }
        if (f2) { tv[2] = tv[3]; tx[2] = tx[3]; }
        if (f3) { tv[3] = tv[4]; tx[3] = tx[4]; }
        if (f4) { tv[4] = SENT; tx[4] = IXMAX; }
    }
}

// ---------------------------------------------------------------------------
extern "C" void kernel_launch(void* const* d_in, const int* in_sizes, int n_in,
                              void* d_out, int out_size, void* d_ws, size_t ws_size,
                              hipStream_t stream) {
    const float* q    = (const float*)d_in[0];   // [B,R,D] fp32
    const float* kb   = (const float*)d_in[1];   // [R,N,D] fp32
    const int*   qid  = (const int*)d_in[2];     // [B]
    const int*   kbid = (const int*)d_in[3];     // [R,N]
    float* out = (float*)d_out;

    float* qn    = (float*)d_ws;                             // R*B*D floats
    float* pvals = qn + (size_t)R_ * B_ * D_;                // R*B*PCAND floats
    int*   pidx  = (int*)(pvals + (size_t)R_ * B_ * PCAND);

    knorm_kernel<<<B_ * R_, 64, 0, stream>>>(q, qn);
    dim3 g2(NTIX, R_);
    ksim_kernel<<<g2, 1024, 0, stream>>>(kb, qn, qid, kbid, pvals, pidx);
    ktop_kernel<<<B_ * R_, 64, 0, stream>>>(pvals, pidx, out);
}

// Round 12
// 540.975 us; speedup vs baseline: 7.2745x; 1.1037x over previous
//
#include <hip/hip_runtime.h>
#include <stddef.h>
#include <stdint.h>

// Problem constants (AnatomicalTextEnhancer): B=16, R=29, D=512, N=20000, k=5
#define B_ 16
#define R_ 29
#define D_ 512
#define DF4 128                            // float4 per row
#define N_ 20000
#define K_ 5
#define TILE 128                           // rows per block (8 waves x 16)
#define NTIX ((N_ + TILE - 1) / TILE)      // 157 tiles per r
#define PCAND (NTIX * K_)                  // 785 candidates per (r,b)
#define NEG_MASK (-1.0e9f)
#define SENT (-3.0e38f)
#define IXMAX 0x7fffffff

// ---------------------------------------------------------------------------
// Kernel 1: L2-normalize queries, write transposed layout qn[r][b][d]
// ---------------------------------------------------------------------------
__global__ __launch_bounds__(64) void knorm_kernel(const float* __restrict__ q,
                                                   float* __restrict__ qn) {
    int pair = blockIdx.x;          // 0 .. B*R-1
    int b = pair / R_;
    int r = pair % R_;
    int lane = threadIdx.x;
    const float4* src = (const float4*)(q + ((size_t)(b * R_ + r)) * D_);
    float4 x0 = src[lane * 2];
    float4 x1 = src[lane * 2 + 1];
    float ss = x0.x * x0.x + x0.y * x0.y + x0.z * x0.z + x0.w * x0.w +
               x1.x * x1.x + x1.y * x1.y + x1.z * x1.z + x1.w * x1.w;
#pragma unroll
    for (int off = 32; off; off >>= 1) ss += __shfl_xor(ss, off);
    float inv = 1.0f / fmaxf(sqrtf(ss), 1e-12f);
    float4 y0, y1;
    y0.x = x0.x * inv; y0.y = x0.y * inv; y0.z = x0.z * inv; y0.w = x0.w * inv;
    y1.x = x1.x * inv; y1.y = x1.y * inv; y1.z = x1.z * inv; y1.w = x1.w * inv;
    float4* dst = (float4*)(qn + ((size_t)(r * B_ + b)) * D_);
    dst[lane * 2] = y0;
    dst[lane * 2 + 1] = y1;
}

// ---------------------------------------------------------------------------
// Kernel 2: occupancy-discriminating variant. 512 threads (8 waves),
// TILE=128 rows, M=2 rows/lane, 8-lane d-split (each load = 8 rows x 128B
// full cache lines). NO launch_bounds cap, NO unroll pragma: minimum live
// state (~50-58 VGPR audited) so the allocator can land <=64 -> 8 waves/SIMD,
// 4 blocks/CU (32KB LDS each) = 32 waves/CU. If it lands 65-128 we get R4
// parity (16 waves/CU) -- the A/B tells us TLP-wall vs MSHR-wall.
// q panel in LDS, broadcast b128 reads (8 unique addrs = all 32 banks,
// measured ZERO conflicts in R8). kb via SGPR base + 32-bit voffset + imm.
// Epilogue: per-wave reg top-5 -> block merge in LDS overlay.
// ---------------------------------------------------------------------------
__global__ __launch_bounds__(512) void ksim_kernel(const float* __restrict__ kb,
                                                   const float* __restrict__ qn,
                                                   const int* __restrict__ qid,
                                                   const int* __restrict__ kbid,
                                                   float* __restrict__ pvals,
                                                   int* __restrict__ pidx) {
    __shared__ float4 qs[B_ * DF4];       // 32 KB q panel (reused for merge)
    const int r = blockIdx.y;
    const int n0 = blockIdx.x * TILE;
    const int tid = threadIdx.x;

    // stage q panel once (coalesced; qn is L2-resident), single barrier
    {
        const float4* src = (const float4*)(qn + (size_t)r * B_ * D_);
#pragma unroll
        for (int i = 0; i < 4; ++i) qs[tid + 512 * i] = src[tid + 512 * i];
    }
    __syncthreads();

    const int w = tid >> 6;               // wave 0..7 (owns 16 rows)
    const int lane = tid & 63;
    const int g = lane >> 3;              // row group 0..7
    const int s = lane & 7;               // d-split 0..7

    const char* kbb = (const char*)(kb + (size_t)r * N_ * D_);  // uniform->SGPR
    unsigned off0, off1;
    {
        int r0 = n0 + w * 16 + g;
        int r1 = r0 + 8;
        int c0 = r0 < N_ ? r0 : N_ - 1;   // clamp tail (masked later)
        int c1 = r1 < N_ ? r1 : N_ - 1;
        off0 = ((unsigned)c0 * D_ + (unsigned)(s * 4)) * 4u;
        off1 = ((unsigned)c1 * D_ + (unsigned)(s * 4)) * 4u;
    }

    float acc0[B_], acc1[B_];
    float nrm0 = 0.0f, nrm1 = 0.0f;
#pragma unroll
    for (int b = 0; b < B_; ++b) { acc0[b] = 0.0f; acc1[b] = 0.0f; }

    // main loop: p = 0..15; lane's chunk = float4 #(8p + s) of each row.
    // no unroll: keeps kv/addr temps minimal; TLP does the latency hiding.
    for (int p = 0; p < 16; ++p) {
        float4 kv0 = *(const float4*)(kbb + off0 + (unsigned)(p * 128));
        float4 kv1 = *(const float4*)(kbb + off1 + (unsigned)(p * 128));
        nrm0 += kv0.x * kv0.x + kv0.y * kv0.y + kv0.z * kv0.z + kv0.w * kv0.w;
        nrm1 += kv1.x * kv1.x + kv1.y * kv1.y + kv1.z * kv1.z + kv1.w * kv1.w;
        const float4* qp = &qs[p * 8 + s];
#pragma unroll
        for (int b = 0; b < B_; ++b) {
            const float4 qv = qp[b * DF4];   // bcast, 1 addr reg + imm offset
            acc0[b] += kv0.x * qv.x + kv0.y * qv.y + kv0.z * qv.z + kv0.w * qv.w;
            acc1[b] += kv1.x * qv.x + kv1.y * qv.y + kv1.z * qv.z + kv1.w * qv.w;
        }
    }

    // reduce partials over the 8 s-lanes (all lanes end with totals)
    nrm0 += __shfl_xor(nrm0, 1); nrm0 += __shfl_xor(nrm0, 2); nrm0 += __shfl_xor(nrm0, 4);
    nrm1 += __shfl_xor(nrm1, 1); nrm1 += __shfl_xor(nrm1, 2); nrm1 += __shfl_xor(nrm1, 4);
#pragma unroll
    for (int b = 0; b < B_; ++b) {
        acc0[b] += __shfl_xor(acc0[b], 1);
        acc0[b] += __shfl_xor(acc0[b], 2);
        acc0[b] += __shfl_xor(acc0[b], 4);
        acc1[b] += __shfl_xor(acc1[b], 1);
        acc1[b] += __shfl_xor(acc1[b], 2);
        acc1[b] += __shfl_xor(acc1[b], 4);
    }

    const int rowi0 = n0 + w * 16 + g;
    const int rowi1 = rowi0 + 8;
    const float rinv0 = 1.0f / fmaxf(sqrtf(nrm0), 1e-12f);
    const float rinv1 = 1.0f / fmaxf(sqrtf(nrm1), 1e-12f);
    const int myid0 = (rowi0 < N_) ? kbid[(size_t)r * N_ + rowi0] : -1;
    const int myid1 = (rowi1 < N_) ? kbid[(size_t)r * N_ + rowi1] : -1;

    __syncthreads();   // all waves done reading qs; reuse it as merge buffer
    float* vbuf = (float*)qs;                 // [16 b][8 w][5]
    int* ibuf = (int*)qs + B_ * 8 * K_;       // [16 b][8 w][5]

    // per-wave top-5 per b over its 16 rows (values 8-fold s-replicated;
    // identical copies keep argmax + removal consistent), written to LDS
    for (int b = 0; b < B_; ++b) {
        const int qb = qid[b];                // uniform -> scalar load
        float v0 = acc0[b] * rinv0;
        float v1 = acc1[b] * rinv1;
        if (myid0 == qb) v0 = NEG_MASK;
        if (myid1 == qb) v1 = NEG_MASK;
        if (rowi0 >= N_) v0 = SENT;
        if (rowi1 >= N_) v1 = SENT;
        for (int k = 0; k < K_; ++k) {
            float bv = v0;
            int bx = rowi0;
            if (v1 > bv || (v1 == bv && rowi1 < bx)) { bv = v1; bx = rowi1; }
#pragma unroll
            for (int off2 = 8; off2 < 64; off2 <<= 1) {
                float ov = __shfl_xor(bv, off2);
                int ox = __shfl_xor(bx, off2);
                if (ov > bv || (ov == bv && ox < bx)) { bv = ov; bx = ox; }
            }
            if (lane == 0) {
                vbuf[(b * 8 + w) * K_ + k] = bv;
                ibuf[(b * 8 + w) * K_ + k] = bx;
            }
            if (rowi0 == bx) v0 = SENT;       // remove winner (all copies)
            if (rowi1 == bx) v1 = SENT;
        }
    }
    __syncthreads();

    // block merge: wave w, half h = lane>>5 handles b = 2w + h (40 cands)
    {
        const int b = 2 * w + (lane >> 5);
        const int li = lane & 31;
        float v0 = vbuf[b * 40 + li];
        int i0 = ibuf[b * 40 + li];
        float v1 = (li < 8) ? vbuf[b * 40 + 32 + li] : SENT;
        int i1 = (li < 8) ? ibuf[b * 40 + 32 + li] : IXMAX;
        for (int k = 0; k < K_; ++k) {
            float bv = v0;
            int bx = i0;
            if (v1 > bv || (v1 == bv && i1 < bx)) { bv = v1; bx = i1; }
#pragma unroll
            for (int off2 = 1; off2 < 32; off2 <<= 1) {   // stays in 32-lane half
                float ov = __shfl_xor(bv, off2);
                int ox = __shfl_xor(bx, off2);
                if (ov > bv || (ov == bv && ox < bx)) { bv = ov; bx = ox; }
            }
            if (li == 0) {
                size_t o = (((size_t)r * B_ + b) * NTIX + blockIdx.x) * K_ + k;
                pvals[o] = bv;
                pidx[o] = bx;
            }
            if (i0 == bx) v0 = SENT;
            if (i1 == bx) v1 = SENT;
        }
    }
}

// ---------------------------------------------------------------------------
// Kernel 3: reduce 785 candidates per (b,r) to final top-5.
// Per-lane running sorted top-5 + 5 shuffle-argmax extractions.
// d_out layout (all float32): scores[B][R] | vals[B][R][5] | idx[B][R][5]
// ---------------------------------------------------------------------------
__global__ __launch_bounds__(64) void ktop_kernel(const float* __restrict__ pvals,
                                                  const int* __restrict__ pidx,
                                                  float* __restrict__ out) {
    int pair = blockIdx.x;      // 0 .. B*R-1
    int b = pair / R_;
    int r = pair % R_;
    int lane = threadIdx.x;
    const float* pv = pvals + ((size_t)r * B_ + b) * PCAND;
    const int* px = pidx + ((size_t)r * B_ + b) * PCAND;

    float tv[5];
    int tx[5];
#pragma unroll
    for (int t = 0; t < 5; ++t) { tv[t] = SENT; tx[t] = IXMAX; }

    for (int j = 0; j < (PCAND + 63) / 64; ++j) {
        int c = lane + 64 * j;
        if (c < PCAND) {
            float v = pv[c];
            int ix = px[c];
            if (v > tv[4] || (v == tv[4] && ix < tx[4])) {
                tv[4] = v; tx[4] = ix;
#pragma unroll
                for (int t = 4; t > 0; --t)
                    if (tv[t] > tv[t - 1] ||
                        (tv[t] == tv[t - 1] && tx[t] < tx[t - 1])) {
                        float fv = tv[t]; tv[t] = tv[t - 1]; tv[t - 1] = fv;
                        int fx = tx[t]; tx[t] = tx[t - 1]; tx[t - 1] = fx;
                    }
            }
        }
    }

#pragma unroll
    for (int k = 0; k < K_; ++k) {
        float bv = tv[0];
        int bx = tx[0];
#pragma unroll
        for (int off = 32; off; off >>= 1) {
            float ov = __shfl_xor(bv, off);
            int ox = __shfl_xor(bx, off);
            if (ov > bv || (ov == bv && ox < bx)) { bv = ov; bx = ox; }
        }
        if (lane == 0) {
            int p = b * R_ + r;
            if (k == 0) out[p] = bv;                       // similarity_scores
            out[B_ * R_ + (size_t)p * K_ + k] = bv;        // top_vals
            out[B_ * R_ + (size_t)B_ * R_ * K_ + (size_t)p * K_ + k] = (float)bx; // top_idx
        }
        // remove winner from this lane's sorted list (forward shift)
        bool f0 = (tx[0] == bx);
        bool f1 = f0 || (tx[1] == bx);
        bool f2 = f1 || (tx[2] == bx);
        bool f3 = f2 || (tx[3] == bx);
        bool f4 = f3 || (tx[4] == bx);
        if (f0) { tv[0] = tv[1]; tx[0] = tx[1]; }
        if (f1) { tv[1] = tv[2]; tx[1] = tx[2]; }
        if (f2) { tv[2] = tv[3]; tx[2] = tx[3]; }
        if (f3) { tv[3] = tv[4]; tx[3] = tx[4]; }
        if (f4) { tv[4] = SENT; tx[4] = IXMAX; }
    }
}

// ---------------------------------------------------------------------------
extern "C" void kernel_launch(void* const* d_in, const int* in_sizes, int n_in,
                              void* d_out, int out_size, void* d_ws, size_t ws_size,
                              hipStream_t stream) {
    const float* q    = (const float*)d_in[0];   // [B,R,D] fp32
    const float* kb   = (const float*)d_in[1];   // [R,N,D] fp32
    const int*   qid  = (const int*)d_in[2];     // [B]
    const int*   kbid = (const int*)d_in[3];     // [R,N]
    float* out = (float*)d_out;

    float* qn    = (float*)d_ws;                             // R*B*D floats
    float* pvals = qn + (size_t)R_ * B_ * D_;                // R*B*PCAND floats
    int*   pidx  = (int*)(pvals + (size_t)R_ * B_ * PCAND);

    knorm_kernel<<<B_ * R_, 64, 0, stream>>>(q, qn);
    dim3 g2(NTIX, R_);
    ksim_kernel<<<g2, 512, 0, stream>>>(kb, qn, qid, kbid, pvals, pidx);
    ktop_kernel<<<B_ * R_, 64, 0, stream>>>(pvals, pidx, out);
}